// Round 6
// baseline (129.783 us; speedup 1.0000x reference)
//
#include <hip/hip_runtime.h>
#include <hip/hip_bf16.h>
#include <stdint.h>

#define B_N 4096
#define V_N 2
#define D_N 1024
#define EPS 1e-8f
#define NSLAB 32                // K-slabs of 32
#define NTASK 272               // sum_{it=0..15} (2*it+2), 272 = 8*34

typedef __attribute__((ext_vector_type(8))) short short8;
typedef __attribute__((ext_vector_type(4))) float f32x4;

__device__ __forceinline__ unsigned int f2mono(float f) {
    unsigned int u = __float_as_uint(f);
    return (u & 0x80000000u) ? ~u : (u | 0x80000000u);
}

__device__ __forceinline__ unsigned short f2bf(float f) {
    __hip_bfloat16 h = __float2bfloat16(f);
    return __builtin_bit_cast(unsigned short, h);
}

__device__ __forceinline__ unsigned long long shfl_xor_u64(unsigned long long v, int m) {
    unsigned int lo = (unsigned int)v, hi = (unsigned int)(v >> 32);
    lo = __shfl_xor(lo, m, 64);
    hi = __shfl_xor(hi, m, 64);
    return ((unsigned long long)hi << 32) | lo;
}

#define GLD16(src, dst) __builtin_amdgcn_global_load_lds(                      \
    (const __attribute__((address_space(1))) unsigned int*)(src),             \
    (__attribute__((address_space(3))) unsigned int*)(dst), 16, 0, 0)

// ---------------- Kernel 1: L2-normalize, emit bf16 (V,B,D) ----------------
__global__ __launch_bounds__(256) void knorm(const float* __restrict__ x,
                                             unsigned short* __restrict__ xbf) {
    int r = blockIdx.x;            // r = b*V + v  (input rows are contiguous)
    int b = r >> 1, v = r & 1;
    const float* row = x + (size_t)r * D_N;
    int t = threadIdx.x;
    float4 val = reinterpret_cast<const float4*>(row)[t];
    float ss = val.x * val.x + val.y * val.y + val.z * val.z + val.w * val.w;
    #pragma unroll
    for (int s = 32; s > 0; s >>= 1) ss += __shfl_xor(ss, s, 64);
    __shared__ float wsum[4];
    if ((t & 63) == 0) wsum[t >> 6] = ss;
    __syncthreads();
    float tot = wsum[0] + wsum[1] + wsum[2] + wsum[3];
    float rn = 1.0f / sqrtf(tot + EPS);
    ushort4 o;
    o.x = f2bf(val.x * rn);
    o.y = f2bf(val.y * rn);
    o.z = f2bf(val.z * rn);
    o.w = f2bf(val.w * rn);
    unsigned short* orow = xbf + ((size_t)v * B_N + b) * D_N;
    reinterpret_cast<ushort4*>(orow)[t] = o;
}

// ------- Kernel 2: per-view X·X^T row-argmax, 256x128 tile, 4 waves --------
// 4 waves (2M x 2N), wave tile 128x64, BK=32 slabs, ring-3 LDS (72 KB).
// 2 blocks/CU co-resident (reg-feasible at 4 waves); one barrier per slab;
// counted vmcnt(6) (T4, never 0 in main loop); T1 XCD chunk; T2 swizzle.

#define STAGE_A(boff, t) do {                                                  \
    const unsigned short* _s = pAsrc + (size_t)(t) * 32;                       \
    unsigned short* _d = lsb + (boff) + wid * 2048;                            \
    GLD16(_s,             _d);                                                 \
    GLD16(_s + 16 * D_N,  _d + 512);                                           \
    GLD16(_s + 32 * D_N,  _d + 1024);                                          \
    GLD16(_s + 48 * D_N,  _d + 1536);                                          \
} while (0)

#define STAGE_B(boff, t) do {                                                  \
    const unsigned short* _s = pBsrc + (size_t)(t) * 32;                       \
    unsigned short* _d = lsb + (boff) + 8192 + wid * 1024;                     \
    GLD16(_s,             _d);                                                 \
    GLD16(_s + 16 * D_N,  _d + 512);                                           \
} while (0)

__global__ __launch_bounds__(256) void kargmax(const unsigned short* __restrict__ xbf,
                                               unsigned long long* __restrict__ rowmax) {
    __shared__ unsigned short lsb[3 * 12288];   // 3 slabs x (A 256x32 + B 128x32) = 72 KB

    const int v = blockIdx.y;
    // T1: chunked XCD swizzle (bijective: 272 = 8*34)
    const int bxr = (blockIdx.x & 7) * (NTASK / 8) + (blockIdx.x >> 3);
    // it*(it+1) <= bxr < (it+1)*(it+2)
    int it = (int)((sqrtf(4.f * (float)bxr + 1.f) - 1.f) * 0.5f);
    while ((it + 1) * (it + 2) <= bxr) it++;
    while (it * (it + 1) > bxr) it--;
    const int jt = bxr - it * (it + 1);          // 0 .. 2*it+1
    const int i0 = it * 256, j0 = jt * 128;
    const unsigned short* Xv = xbf + (size_t)v * B_N * D_N;

    const int tid = threadIdx.x;
    const int wid = tid >> 6, lane = tid & 63;
    const int wr = wid >> 1, wc = wid & 1;       // 2M x 2N waves

    f32x4 acc[8][4];
    #pragma unroll
    for (int m = 0; m < 8; m++)
        #pragma unroll
        for (int n = 0; n < 4; n++) acc[m][n] = (f32x4){0.f, 0.f, 0.f, 0.f};

    // Write side: lane l -> row l>>2 of a 16-row chunk, linear slot l&3;
    // source K-chunk = (l&3) ^ swz(row), swz(row) = (row>>1)&3 = (l>>3)&3.
    const int csw = ((lane & 3) ^ ((lane >> 3) & 3)) * 8;
    const unsigned short* pAsrc = Xv + (size_t)(i0 + wid * 64 + (lane >> 2)) * D_N + csw;
    const unsigned short* pBsrc = Xv + (size_t)(j0 + wid * 32 + (lane >> 2)) * D_N + csw;

    // Read side: chunk lane>>4 at row with row%16 = lane&15:
    // slot = (lane>>4) ^ ((row>>1)&3)
    const int rslot = (((lane >> 4) ^ ((lane & 15) >> 1)) & 3) * 8;

    // ---- Prologue: slabs 0,1 in flight (12 loads/wave) ----
    STAGE_A(0, 0);     STAGE_B(0, 0);
    STAGE_A(12288, 1); STAGE_B(12288, 1);
    asm volatile("s_waitcnt vmcnt(6)" ::: "memory");   // slab 0 landed
    __builtin_amdgcn_s_barrier();

    // ---- Main: one barrier/slab, stage t+2, counted vmcnt(6) ----
    int cb = 0, sb = 24576;                  // byte... short offsets of cur/stage bufs
    for (int t = 0; t < NSLAB; ++t) {
        if (t < NSLAB - 2) { STAGE_A(sb, t + 2); STAGE_B(sb, t + 2); }
        const unsigned short* la = lsb + cb;
        const unsigned short* lb = la + 8192;
        short8 af[4], bfr[4];
        #pragma unroll
        for (int n = 0; n < 4; n++)
            bfr[n] = *reinterpret_cast<const short8*>(
                &lb[(wc * 64 + n * 16 + (lane & 15)) * 32 + rslot]);
        #pragma unroll
        for (int m = 0; m < 4; m++)
            af[m] = *reinterpret_cast<const short8*>(
                &la[(wr * 128 + m * 16 + (lane & 15)) * 32 + rslot]);
        __builtin_amdgcn_s_setprio(1);
        #pragma unroll
        for (int m = 0; m < 4; m++)
            #pragma unroll
            for (int n = 0; n < 4; n++)
                acc[m][n] = __builtin_amdgcn_mfma_f32_16x16x32_bf16(
                    af[m], bfr[n], acc[m][n], 0, 0, 0);
        __builtin_amdgcn_s_setprio(0);
        #pragma unroll
        for (int m = 0; m < 4; m++)
            af[m] = *reinterpret_cast<const short8*>(
                &la[(wr * 128 + (m + 4) * 16 + (lane & 15)) * 32 + rslot]);
        __builtin_amdgcn_s_setprio(1);
        #pragma unroll
        for (int m = 0; m < 4; m++)
            #pragma unroll
            for (int n = 0; n < 4; n++)
                acc[m + 4][n] = __builtin_amdgcn_mfma_f32_16x16x32_bf16(
                    af[m], bfr[n], acc[m + 4][n], 0, 0, 0);
        __builtin_amdgcn_s_setprio(0);
        if (t < NSLAB - 2)      asm volatile("s_waitcnt vmcnt(6)" ::: "memory");
        else if (t == NSLAB - 2) asm volatile("s_waitcnt vmcnt(0)" ::: "memory");
        __builtin_amdgcn_s_barrier();
        cb += 12288; if (cb == 36864) cb = 0;
        sb += 12288; if (sb == 36864) sb = 0;
    }

    // ---- Epilogue A: row side (rows i0.., cols j0..) ----
    // C/D layout: col = lane&15, row = (lane>>4)*4 + reg  [m89/m91-verified]
    #pragma unroll
    for (int m = 0; m < 8; m++) {
        int rbase = i0 + wr * 128 + m * 16;
        #pragma unroll
        for (int j = 0; j < 4; j++) {
            int grow = rbase + (lane >> 4) * 4 + j;
            unsigned long long best = 0ull;
            #pragma unroll
            for (int n = 0; n < 4; n++) {
                int gcol = j0 + wc * 64 + n * 16 + (lane & 15);
                float vdot = acc[m][n][j];
                unsigned long long p = (grow == gcol)
                    ? 0ull
                    : ((unsigned long long)f2mono(vdot) << 32) | (unsigned int)(~(unsigned int)gcol);
                best = p > best ? p : best;
            }
            #pragma unroll
            for (int s = 1; s < 16; s <<= 1) {
                unsigned long long o = shfl_xor_u64(best, s);
                best = o > best ? o : best;
            }
            if ((lane & 15) == 0)
                atomicMax(&rowmax[(size_t)v * B_N + grow], best);
        }
    }

    // ---- Epilogue B: transposed side (rows j0.., cols i0..), always ----
    #pragma unroll
    for (int n = 0; n < 4; n++) {
        int growT = j0 + wc * 64 + n * 16 + (lane & 15);
        unsigned long long best = 0ull;
        #pragma unroll
        for (int m = 0; m < 8; m++) {
            int ibase = i0 + wr * 128 + m * 16 + (lane >> 4) * 4;
            #pragma unroll
            for (int j = 0; j < 4; j++) {
                int gi = ibase + j;
                float vdot = acc[m][n][j];
                unsigned long long p = (gi == growT)
                    ? 0ull
                    : ((unsigned long long)f2mono(vdot) << 32) | (unsigned int)(~(unsigned int)gi);
                best = p > best ? p : best;
            }
        }
        #pragma unroll
        for (int s = 16; s < 64; s <<= 1) {
            unsigned long long o = shfl_xor_u64(best, s);
            best = o > best ? o : best;
        }
        if (lane < 16)
            atomicMax(&rowmax[(size_t)v * B_N + growT], best);
    }
}

// ------ Kernel 3: exact fp32 distance for selected pairs, per-row loss -----
__global__ __launch_bounds__(256) void kdist(const float* __restrict__ x,
                                             const unsigned long long* __restrict__ rowmax,
                                             float* __restrict__ loss) {
    int idx = blockIdx.x;              // v*B + b
    int v = idx >> 12;
    int b = idx & (B_N - 1);
    unsigned long long p = rowmax[idx];
    int j = (int)(~(unsigned int)(p & 0xffffffffull));
    const float* pa = x + ((size_t)b * V_N + v) * D_N;
    const float* pc = x + ((size_t)j * V_N + v) * D_N;
    int t = threadIdx.x;
    float4 a = reinterpret_cast<const float4*>(pa)[t];
    float4 c = reinterpret_cast<const float4*>(pc)[t];
    float saa = a.x * a.x + a.y * a.y + a.z * a.z + a.w * a.w;
    float scc = c.x * c.x + c.y * c.y + c.z * c.z + c.w * c.w;
    float sac = a.x * c.x + a.y * c.y + a.z * c.z + a.w * c.w;
    #pragma unroll
    for (int s = 32; s > 0; s >>= 1) {
        saa += __shfl_xor(saa, s, 64);
        scc += __shfl_xor(scc, s, 64);
        sac += __shfl_xor(sac, s, 64);
    }
    __shared__ float r0[4], r1[4], r2[4];
    if ((t & 63) == 0) { r0[t >> 6] = saa; r1[t >> 6] = scc; r2[t >> 6] = sac; }
    __syncthreads();
    if (t == 0) {
        saa = r0[0] + r0[1] + r0[2] + r0[3];
        scc = r1[0] + r1[1] + r1[2] + r1[3];
        sac = r2[0] + r2[1] + r2[2] + r2[3];
        float na = sqrtf(saa + EPS), nc = sqrtf(scc + EPS);
        float d2 = saa / (na * na) + scc / (nc * nc) - 2.0f * sac / (na * nc);
        d2 = fmaxf(d2, 0.0f);
        float dist = sqrtf(d2);
        loss[idx] = -logf(dist + EPS);
    }
}

// --------------- Kernel 4: deterministic reduction to scalar ---------------
__global__ __launch_bounds__(256) void kreduce(const float* __restrict__ loss,
                                               float* __restrict__ out) {
    __shared__ float s[256];
    float acc = 0.f;
    for (int i = threadIdx.x; i < V_N * B_N; i += 256) acc += loss[i];
    s[threadIdx.x] = acc;
    __syncthreads();
    #pragma unroll
    for (int step = 128; step > 0; step >>= 1) {
        if (threadIdx.x < step) s[threadIdx.x] += s[threadIdx.x + step];
        __syncthreads();
    }
    if (threadIdx.x == 0) out[0] = s[0] * (1.0f / (float)B_N);
}

extern "C" void kernel_launch(void* const* d_in, const int* in_sizes, int n_in,
                              void* d_out, int out_size, void* d_ws, size_t ws_size,
                              hipStream_t stream) {
    const float* x = (const float*)d_in[0];
    float* out = (float*)d_out;
    char* ws = (char*)d_ws;

    unsigned short* xbf = (unsigned short*)ws;                          // 16 MB
    unsigned long long* rowmax = (unsigned long long*)(ws + 16777216);  // 64 KB
    float* loss = (float*)(ws + 16777216 + 65536);                      // 32 KB

    hipMemsetAsync(rowmax, 0, (size_t)V_N * B_N * sizeof(unsigned long long), stream);
    knorm<<<B_N * V_N, 256, 0, stream>>>(x, xbf);
    kargmax<<<dim3(NTASK, V_N), 256, 0, stream>>>(xbf, rowmax);
    kdist<<<V_N * B_N, 256, 0, stream>>>(x, rowmax, loss);
    kreduce<<<1, 256, 0, stream>>>(loss, out);
}

// Round 7
// 111.812 us; speedup vs baseline: 1.1607x; 1.1607x over previous
//
#include <hip/hip_runtime.h>
#include <hip/hip_bf16.h>
#include <stdint.h>

#define B_N 4096
#define V_N 2
#define D_N 1024
#define EPS 1e-8f
#define NT2 16                  // 4096/256 tiles per dim
#define NTRI2 (NT2*(NT2+1)/2)   // 136 = 8*17 -> clean XCD chunking

typedef __attribute__((ext_vector_type(8))) short short8;
typedef __attribute__((ext_vector_type(4))) float f32x4;

__device__ __forceinline__ unsigned int f2mono(float f) {
    unsigned int u = __float_as_uint(f);
    return (u & 0x80000000u) ? ~u : (u | 0x80000000u);
}

__device__ __forceinline__ unsigned short f2bf(float f) {
    __hip_bfloat16 h = __float2bfloat16(f);
    return __builtin_bit_cast(unsigned short, h);
}

__device__ __forceinline__ unsigned long long shfl_xor_u64(unsigned long long v, int m) {
    unsigned int lo = (unsigned int)v, hi = (unsigned int)(v >> 32);
    lo = __shfl_xor(lo, m, 64);
    hi = __shfl_xor(hi, m, 64);
    return ((unsigned long long)hi << 32) | lo;
}

#define GLD16(src, dst) __builtin_amdgcn_global_load_lds(                      \
    (const __attribute__((address_space(1))) unsigned int*)(src),             \
    (__attribute__((address_space(3))) unsigned int*)(dst), 16, 0, 0)

// ---------------- Kernel 1: L2-normalize, emit bf16 (V,B,D) ----------------
__global__ __launch_bounds__(256) void knorm(const float* __restrict__ x,
                                             unsigned short* __restrict__ xbf) {
    int r = blockIdx.x;            // r = b*V + v  (input rows are contiguous)
    int b = r >> 1, v = r & 1;
    const float* row = x + (size_t)r * D_N;
    int t = threadIdx.x;
    float4 val = reinterpret_cast<const float4*>(row)[t];
    float ss = val.x * val.x + val.y * val.y + val.z * val.z + val.w * val.w;
    #pragma unroll
    for (int s = 32; s > 0; s >>= 1) ss += __shfl_xor(ss, s, 64);
    __shared__ float wsum[4];
    if ((t & 63) == 0) wsum[t >> 6] = ss;
    __syncthreads();
    float tot = wsum[0] + wsum[1] + wsum[2] + wsum[3];
    float rn = 1.0f / sqrtf(tot + EPS);
    ushort4 o;
    o.x = f2bf(val.x * rn);
    o.y = f2bf(val.y * rn);
    o.z = f2bf(val.z * rn);
    o.w = f2bf(val.w * rn);
    unsigned short* orow = xbf + ((size_t)v * B_N + b) * D_N;
    reinterpret_cast<ushort4*>(orow)[t] = o;
}

// ---- Kernel 2: X·X^T row-argmax, m201-style 256^2 8-phase template -------
// 8 waves (2M x 4N), wave tile 128x64, BK=64 K-tiles (16 total), 2 LDS bufs
// of 4 half-tiles {A0,A1,B0,B1} each 128x64 bf16 -> 128 KB.
// Half-tile stagger (derived; t = even tile in buf0, t+1 in buf1):
//   P1 stages buf1.A1(t+1)   [old A1(t-1) last read P8(prev)]
//   P2 stages buf1.B1(t+1)   [old B1(t-1) last read P8(prev)]
//   P3 stages buf0.A0(t+2)   [A0(t) last read P1]
//   P4 stages buf0.B0(t+2)   [B0(t) last read P1]   + vmcnt(4)
//   P5 stages buf0.A1(t+2)   [A1(t) last read P3]
//   P6 stages buf0.B1(t+2)   [B1(t) last read P2]
//   P7 stages buf1.A0(t+3)   [A0(t+1) last read P6? reads P5/P6 -> safe]
//   P8 stages buf1.B0(t+3)   [B0(t+1) last read P7]  + vmcnt(4)
// vmcnt(4)@P4: leaves P3,P4's 4 loads -> buf1 tile t+1 fully landed for P5.
// vmcnt(4)@P8: leaves P7,P8's 4 loads -> buf0 tile t+2 fully landed for P1'.
// Last iter (i=7): P3..P8 stages off; P4 uses vmcnt(0) (covers P1,P2's t15 loads).

#define BARR __builtin_amdgcn_s_barrier()
#define LGK0 do { asm volatile("s_waitcnt lgkmcnt(0)" ::: "memory");           \
                  __builtin_amdgcn_sched_barrier(0); } while (0)

// stage one half-tile: buf in {0,1}, half in {0,1}, isB in {0,1}, K-tile t
#define STG(buf, half, isB, t) do {                                           \
    const unsigned short* _p = ((isB) ? pB : pA) + (half) * (128 * D_N) + (t) * 64; \
    unsigned short* _d = lsb + (buf) * 32768 + ((isB) * 2 + (half)) * 8192 + wid * 512; \
    GLD16(_p, _d);                                                            \
    GLD16(_p + 64 * D_N, _d + 4096);                                          \
} while (0)

// read A-frags (m = MH*4 .. +3) from buf
#define RD_A(buf, MH) do {                                                    \
    const unsigned short* _a = lsb + (buf) * 32768 + wr * 8192 + arow + (MH) * 4096; \
    _Pragma("unroll")                                                         \
    for (int mm = 0; mm < 4; mm++) {                                          \
        af0[mm] = *reinterpret_cast<const short8*>(_a + mm * 1024 + s0);      \
        af1[mm] = *reinterpret_cast<const short8*>(_a + mm * 1024 + s1);      \
    }                                                                         \
} while (0)

#define RD_B0(buf) do {                                                       \
    const unsigned short* _b = lsb + (buf) * 32768 + (2 + (wc >> 1)) * 8192   \
                               + (wc & 1) * 4096 + arow;                      \
    _Pragma("unroll")                                                         \
    for (int nn = 0; nn < 2; nn++) {                                          \
        b00[nn] = *reinterpret_cast<const short8*>(_b + nn * 1024 + s0);      \
        b01[nn] = *reinterpret_cast<const short8*>(_b + nn * 1024 + s1);      \
    }                                                                         \
} while (0)

#define RD_B1(buf) do {                                                       \
    const unsigned short* _b = lsb + (buf) * 32768 + (2 + (wc >> 1)) * 8192   \
                               + (wc & 1) * 4096 + arow;                      \
    _Pragma("unroll")                                                         \
    for (int nn = 0; nn < 2; nn++) {                                          \
        b10[nn] = *reinterpret_cast<const short8*>(_b + (2 + nn) * 1024 + s0);\
        b11[nn] = *reinterpret_cast<const short8*>(_b + (2 + nn) * 1024 + s1);\
    }                                                                         \
} while (0)

#define MM(MH, NH, Bk0, Bk1) do {                                             \
    __builtin_amdgcn_s_setprio(1);                                            \
    _Pragma("unroll")                                                         \
    for (int mm = 0; mm < 4; mm++)                                            \
        _Pragma("unroll")                                                     \
        for (int nn = 0; nn < 2; nn++) {                                      \
            acc[(MH)*4+mm][(NH)*2+nn] = __builtin_amdgcn_mfma_f32_16x16x32_bf16( \
                af0[mm], Bk0[nn], acc[(MH)*4+mm][(NH)*2+nn], 0, 0, 0);        \
            acc[(MH)*4+mm][(NH)*2+nn] = __builtin_amdgcn_mfma_f32_16x16x32_bf16( \
                af1[mm], Bk1[nn], acc[(MH)*4+mm][(NH)*2+nn], 0, 0, 0);        \
        }                                                                     \
    __builtin_amdgcn_s_setprio(0);                                            \
} while (0)

#define ITER(i, SON, VM4) do {                                                \
    /* P1: q(0,0) buf0 */                                                     \
    RD_A(0, 0); RD_B0(0);                                                     \
    STG(1, 1, 0, 2*(i)+1);                                                    \
    asm volatile("s_waitcnt lgkmcnt(8)" ::: "memory");                        \
    BARR; LGK0; MM(0, 0, b00, b01); BARR;                                     \
    /* P2: q(0,1) buf0 */                                                     \
    RD_B1(0);                                                                 \
    STG(1, 1, 1, 2*(i)+1);                                                    \
    BARR; LGK0; MM(0, 1, b10, b11); BARR;                                     \
    /* P3: q(1,0) buf0 */                                                     \
    RD_A(0, 1);                                                               \
    if (SON) STG(0, 0, 0, 2*(i)+2);                                           \
    BARR; LGK0; MM(1, 0, b00, b01); BARR;                                     \
    /* P4: q(1,1) buf0 */                                                     \
    if (SON) STG(0, 0, 1, 2*(i)+2);                                           \
    BARR; LGK0; MM(1, 1, b10, b11);                                           \
    if (VM4) { asm volatile("s_waitcnt vmcnt(4)" ::: "memory"); }             \
    else     { asm volatile("s_waitcnt vmcnt(0)" ::: "memory"); }             \
    BARR;                                                                     \
    /* P5: q(0,0) buf1 */                                                     \
    RD_A(1, 0); RD_B0(1);                                                     \
    if (SON) STG(0, 1, 0, 2*(i)+2);                                           \
    asm volatile("s_waitcnt lgkmcnt(8)" ::: "memory");                        \
    BARR; LGK0; MM(0, 0, b00, b01); BARR;                                     \
    /* P6: q(0,1) buf1 */                                                     \
    RD_B1(1);                                                                 \
    if (SON) STG(0, 1, 1, 2*(i)+2);                                           \
    BARR; LGK0; MM(0, 1, b10, b11); BARR;                                     \
    /* P7: q(1,0) buf1 */                                                     \
    RD_A(1, 1);                                                               \
    if (SON) STG(1, 0, 0, 2*(i)+3);                                           \
    BARR; LGK0; MM(1, 0, b00, b01); BARR;                                     \
    /* P8: q(1,1) buf1 */                                                     \
    if (SON) STG(1, 0, 1, 2*(i)+3);                                           \
    BARR; LGK0; MM(1, 1, b10, b11);                                           \
    if (VM4) { asm volatile("s_waitcnt vmcnt(4)" ::: "memory"); }             \
    else     { asm volatile("s_waitcnt vmcnt(0)" ::: "memory"); }             \
    BARR;                                                                     \
} while (0)

__global__ __launch_bounds__(512, 2) void kargmax(const unsigned short* __restrict__ xbf,
                                                  unsigned long long* __restrict__ rowmax) {
    __shared__ unsigned short lsb[65536];   // 2 bufs x 4 halves x 128x64 bf16 = 128 KB

    const int v = blockIdx.y;
    // T1: chunked XCD swizzle (bijective: 136 = 8*17)
    const int bxr = (blockIdx.x & 7) * (NTRI2 / 8) + (blockIdx.x >> 3);
    int ti = (int)((sqrtf(8.f * (float)bxr + 1.f) - 1.f) * 0.5f);
    while ((ti + 1) * (ti + 2) / 2 <= bxr) ti++;
    while (ti * (ti + 1) / 2 > bxr) ti--;
    const int tj = bxr - ti * (ti + 1) / 2;
    const int i0 = ti * 256, j0 = tj * 256;
    const bool diag = (ti == tj);
    const unsigned short* Xv = xbf + (size_t)v * B_N * D_N;

    const int tid = threadIdx.x;
    const int wid = tid >> 6, lane = tid & 63;
    const int wr = wid >> 2, wc = wid & 3;       // 2M x 4N waves

    f32x4 acc[8][4];
    #pragma unroll
    for (int m = 0; m < 8; m++)
        #pragma unroll
        for (int n = 0; n < 4; n++) acc[m][n] = (f32x4){0.f, 0.f, 0.f, 0.f};

    // ---- staging addressing (write side, rule #21: pre-swizzled source) ----
    // thread covers rows wid*8 + (lane>>3) (+64 for chunk1), physical slot lane&7;
    // source K-chunk = (lane&7) ^ (row&7), row&7 = (lane>>3)
    const int csw = ((lane & 7) ^ (lane >> 3)) * 8;
    const unsigned short* pA = Xv + (size_t)(i0 + wid * 8 + (lane >> 3)) * D_N + csw;
    const unsigned short* pB = Xv + (size_t)(j0 + wid * 8 + (lane >> 3)) * D_N + csw;

    // ---- read addressing: logical slot (kk*4 + lane>>4) ^ (row&7), row&7=lane&7
    const int s0 = (((lane >> 4)) ^ (lane & 7)) * 8;
    const int s1 = ((4 + (lane >> 4)) ^ (lane & 7)) * 8;
    const int arow = (lane & 15) * 64;

    short8 af0[4], af1[4], b00[2], b01[2], b10[2], b11[2];

    // ---- Prologue: buf0 = tile 0 (all 4 halves), buf1 = tile 1 (A0,B0) ----
    STG(0, 0, 0, 0); STG(0, 0, 1, 0); STG(0, 1, 0, 0); STG(0, 1, 1, 0);
    STG(1, 0, 0, 1); STG(1, 0, 1, 1);
    asm volatile("s_waitcnt vmcnt(4)" ::: "memory");   // buf0 landed
    BARR;

    #pragma unroll 1
    for (int i = 0; i < 7; ++i) ITER(i, 1, 1);
    ITER(7, 0, 0);

    // ---- Epilogue A: row side (rows i0.., cols j0..) ----
    // C/D layout: col = lane&15, row = (lane>>4)*4 + reg  [m89/m91-verified]
    #pragma unroll
    for (int m = 0; m < 8; m++) {
        int rbase = i0 + wr * 128 + m * 16;
        #pragma unroll
        for (int j = 0; j < 4; j++) {
            int grow = rbase + (lane >> 4) * 4 + j;
            unsigned long long best = 0ull;
            #pragma unroll
            for (int n = 0; n < 4; n++) {
                int gcol = j0 + wc * 64 + n * 16 + (lane & 15);
                float vdot = acc[m][n][j];
                unsigned long long p = (grow == gcol)
                    ? 0ull
                    : ((unsigned long long)f2mono(vdot) << 32) | (unsigned int)(~(unsigned int)gcol);
                best = p > best ? p : best;
            }
            #pragma unroll
            for (int s = 1; s < 16; s <<= 1) {
                unsigned long long o = shfl_xor_u64(best, s);
                best = o > best ? o : best;
            }
            if ((lane & 15) == 0)
                atomicMax(&rowmax[(size_t)v * B_N + grow], best);
        }
    }

    // ---- Epilogue B: transposed side (rows j0.., cols i0..), off-diag only ----
    if (!diag) {
        #pragma unroll
        for (int n = 0; n < 4; n++) {
            int growT = j0 + wc * 64 + n * 16 + (lane & 15);
            unsigned long long best = 0ull;
            #pragma unroll
            for (int m = 0; m < 8; m++) {
                int ibase = i0 + wr * 128 + m * 16 + (lane >> 4) * 4;
                #pragma unroll
                for (int j = 0; j < 4; j++) {
                    int gi = ibase + j;
                    float vdot = acc[m][n][j];
                    unsigned long long p =
                        ((unsigned long long)f2mono(vdot) << 32) | (unsigned int)(~(unsigned int)gi);
                    best = p > best ? p : best;
                }
            }
            #pragma unroll
            for (int s = 16; s < 64; s <<= 1) {
                unsigned long long o = shfl_xor_u64(best, s);
                best = o > best ? o : best;
            }
            if (lane < 16)
                atomicMax(&rowmax[(size_t)v * B_N + growT], best);
        }
    }
}

// ------ Kernel 3: exact fp32 distance for selected pairs, per-row loss -----
__global__ __launch_bounds__(256) void kdist(const float* __restrict__ x,
                                             const unsigned long long* __restrict__ rowmax,
                                             float* __restrict__ loss) {
    int idx = blockIdx.x;              // v*B + b
    int v = idx >> 12;
    int b = idx & (B_N - 1);
    unsigned long long p = rowmax[idx];
    int j = (int)(~(unsigned int)(p & 0xffffffffull));
    const float* pa = x + ((size_t)b * V_N + v) * D_N;
    const float* pc = x + ((size_t)j * V_N + v) * D_N;
    int t = threadIdx.x;
    float4 a = reinterpret_cast<const float4*>(pa)[t];
    float4 c = reinterpret_cast<const float4*>(pc)[t];
    float saa = a.x * a.x + a.y * a.y + a.z * a.z + a.w * a.w;
    float scc = c.x * c.x + c.y * c.y + c.z * c.z + c.w * c.w;
    float sac = a.x * c.x + a.y * c.y + a.z * c.z + a.w * c.w;
    #pragma unroll
    for (int s = 32; s > 0; s >>= 1) {
        saa += __shfl_xor(saa, s, 64);
        scc += __shfl_xor(scc, s, 64);
        sac += __shfl_xor(sac, s, 64);
    }
    __shared__ float r0[4], r1[4], r2[4];
    if ((t & 63) == 0) { r0[t >> 6] = saa; r1[t >> 6] = scc; r2[t >> 6] = sac; }
    __syncthreads();
    if (t == 0) {
        saa = r0[0] + r0[1] + r0[2] + r0[3];
        scc = r1[0] + r1[1] + r1[2] + r1[3];
        sac = r2[0] + r2[1] + r2[2] + r2[3];
        float na = sqrtf(saa + EPS), nc = sqrtf(scc + EPS);
        float d2 = saa / (na * na) + scc / (nc * nc) - 2.0f * sac / (na * nc);
        d2 = fmaxf(d2, 0.0f);
        float dist = sqrtf(d2);
        loss[idx] = -logf(dist + EPS);
    }
}

// --------------- Kernel 4: deterministic reduction to scalar ---------------
__global__ __launch_bounds__(256) void kreduce(const float* __restrict__ loss,
                                               float* __restrict__ out) {
    __shared__ float s[256];
    float acc = 0.f;
    for (int i = threadIdx.x; i < V_N * B_N; i += 256) acc += loss[i];
    s[threadIdx.x] = acc;
    __syncthreads();
    #pragma unroll
    for (int step = 128; step > 0; step >>= 1) {
        if (threadIdx.x < step) s[threadIdx.x] += s[threadIdx.x + step];
        __syncthreads();
    }
    if (threadIdx.x == 0) out[0] = s[0] * (1.0f / (float)B_N);
}

extern "C" void kernel_launch(void* const* d_in, const int* in_sizes, int n_in,
                              void* d_out, int out_size, void* d_ws, size_t ws_size,
                              hipStream_t stream) {
    const float* x = (const float*)d_in[0];
    float* out = (float*)d_out;
    char* ws = (char*)d_ws;

    unsigned short* xbf = (unsigned short*)ws;                          // 16 MB
    unsigned long long* rowmax = (unsigned long long*)(ws + 16777216);  // 64 KB
    float* loss = (float*)(ws + 16777216 + 65536);                      // 32 KB

    hipMemsetAsync(rowmax, 0, (size_t)V_N * B_N * sizeof(unsigned long long), stream);
    knorm<<<B_N * V_N, 256, 0, stream>>>(x, xbf);
    kargmax<<<dim3(NTRI2, V_N), 512, 0, stream>>>(xbf, rowmax);
    kdist<<<V_N * B_N, 256, 0, stream>>>(x, rowmax, loss);
    kreduce<<<1, 256, 0, stream>>>(loss, out);
}

// Round 8
// 95.810 us; speedup vs baseline: 1.3546x; 1.1670x over previous
//
#include <hip/hip_runtime.h>
#include <hip/hip_bf16.h>
#include <stdint.h>

#define B_N 4096
#define V_N 2
#define D_N 1024
#define EPS 1e-8f
#define NT 32                // 4096/128 tiles per dim
#define NTRI (NT*(NT+1)/2)   // 528 = 8*66 -> clean XCD chunking

typedef __attribute__((ext_vector_type(8))) short short8;
typedef __attribute__((ext_vector_type(4))) float f32x4;

__device__ __forceinline__ unsigned int f2mono(float f) {
    unsigned int u = __float_as_uint(f);
    return (u & 0x80000000u) ? ~u : (u | 0x80000000u);
}

__device__ __forceinline__ float mono2f(unsigned int m) {
    unsigned int u = (m & 0x80000000u) ? (m ^ 0x80000000u) : ~m;
    return __uint_as_float(u);
}

__device__ __forceinline__ unsigned short f2bf(float f) {
    __hip_bfloat16 h = __float2bfloat16(f);
    return __builtin_bit_cast(unsigned short, h);
}

__device__ __forceinline__ unsigned long long shfl_xor_u64(unsigned long long v, int m) {
    unsigned int lo = (unsigned int)v, hi = (unsigned int)(v >> 32);
    lo = __shfl_xor(lo, m, 64);
    hi = __shfl_xor(hi, m, 64);
    return ((unsigned long long)hi << 32) | lo;
}

// ---------------- Kernel 1: L2-normalize, emit bf16 (V,B,D) ----------------
__global__ __launch_bounds__(256) void knorm(const float* __restrict__ x,
                                             unsigned short* __restrict__ xbf) {
    int r = blockIdx.x;            // r = b*V + v  (input rows are contiguous)
    int b = r >> 1, v = r & 1;
    const float* row = x + (size_t)r * D_N;
    int t = threadIdx.x;
    float4 val = reinterpret_cast<const float4*>(row)[t];
    float ss = val.x * val.x + val.y * val.y + val.z * val.z + val.w * val.w;
    #pragma unroll
    for (int s = 32; s > 0; s >>= 1) ss += __shfl_xor(ss, s, 64);
    __shared__ float wsum[4];
    if ((t & 63) == 0) wsum[t >> 6] = ss;
    __syncthreads();
    float tot = wsum[0] + wsum[1] + wsum[2] + wsum[3];
    float rn = 1.0f / sqrtf(tot + EPS);
    ushort4 o;
    o.x = f2bf(val.x * rn);
    o.y = f2bf(val.y * rn);
    o.z = f2bf(val.z * rn);
    o.w = f2bf(val.w * rn);
    unsigned short* orow = xbf + ((size_t)v * B_N + b) * D_N;
    reinterpret_cast<ushort4*>(orow)[t] = o;
}

// ------- Kernel 2: per-view X·X^T, row-wise argmax, symmetric tiles --------
// Round-1-proven structure: 128x128 tile, 4 waves (2x2), 16x16x32 bf16 MFMA,
// BK=64, single 32KB LDS buffer, LINEAR layout (conflicts accepted per m97/m98),
// stage -> sync -> compute -> sync. Triangle tiles + XCD chunking on top.
__global__ __launch_bounds__(256, 4) void kargmax(const unsigned short* __restrict__ xbf,
                                                  unsigned long long* __restrict__ rowmax) {
    __shared__ unsigned short lA[128 * 64];
    __shared__ unsigned short lB[128 * 64];
    const int v = blockIdx.y;
    // T1: chunked XCD swizzle (bijective: 528 = 8*66)
    const int bx = (blockIdx.x & 7) * (NTRI / 8) + (blockIdx.x >> 3);
    int ti = (int)((sqrtf(8.f * (float)bx + 1.f) - 1.f) * 0.5f);
    while ((ti + 1) * (ti + 2) / 2 <= bx) ti++;
    while (ti * (ti + 1) / 2 > bx) ti--;
    const int tj = bx - ti * (ti + 1) / 2;
    const int i0 = ti * 128;
    const int j0 = tj * 128;
    const bool diag = (ti == tj);
    const unsigned short* Xv = xbf + (size_t)v * B_N * D_N;

    const int tid = threadIdx.x;
    const int wid = tid >> 6, lane = tid & 63;
    const int wr = wid >> 1, wc = wid & 1;

    f32x4 acc[4][4];
    #pragma unroll
    for (int m = 0; m < 4; m++)
        #pragma unroll
        for (int n = 0; n < 4; n++) acc[m][n] = (f32x4){0.f, 0.f, 0.f, 0.f};

    const int srow = lane >> 3;         // 0..7 within an 8-row chunk
    const int scol = (lane & 7) * 8;    // linear 16B slot (no swizzle)

    for (int kt = 0; kt < D_N; kt += 64) {
        #pragma unroll
        for (int c = 0; c < 4; ++c) {
            int chunk = wid * 4 + c;    // 0..15, 8 rows each
            int row = chunk * 8 + srow;
            const unsigned short* ga = Xv + (size_t)(i0 + row) * D_N + kt + scol;
            const unsigned short* gb = Xv + (size_t)(j0 + row) * D_N + kt + scol;
            __builtin_amdgcn_global_load_lds(
                (const __attribute__((address_space(1))) unsigned int*)ga,
                (__attribute__((address_space(3))) unsigned int*)&lA[chunk * 512], 16, 0, 0);
            __builtin_amdgcn_global_load_lds(
                (const __attribute__((address_space(1))) unsigned int*)gb,
                (__attribute__((address_space(3))) unsigned int*)&lB[chunk * 512], 16, 0, 0);
        }
        __syncthreads();
        #pragma unroll
        for (int kk = 0; kk < 64; kk += 32) {
            short8 af[4], bfr[4];
            #pragma unroll
            for (int m = 0; m < 4; m++)
                af[m] = *reinterpret_cast<const short8*>(
                    &lA[(wr * 64 + m * 16 + (lane & 15)) * 64 + kk + (lane >> 4) * 8]);
            #pragma unroll
            for (int n = 0; n < 4; n++)
                bfr[n] = *reinterpret_cast<const short8*>(
                    &lB[(wc * 64 + n * 16 + (lane & 15)) * 64 + kk + (lane >> 4) * 8]);
            #pragma unroll
            for (int m = 0; m < 4; m++)
                #pragma unroll
                for (int n = 0; n < 4; n++)
                    acc[m][n] = __builtin_amdgcn_mfma_f32_16x16x32_bf16(af[m], bfr[n], acc[m][n], 0, 0, 0);
        }
        __syncthreads();
    }

    // ---- Epilogue A: row side (rows i0.., cols j0..) ----
    // C/D layout: col = lane&15, row = (lane>>4)*4 + reg  [m89/m91-verified]
    #pragma unroll
    for (int m = 0; m < 4; m++) {
        int rbase = i0 + wr * 64 + m * 16;
        #pragma unroll
        for (int j = 0; j < 4; j++) {
            int grow = rbase + (lane >> 4) * 4 + j;
            unsigned long long best = 0ull;
            #pragma unroll
            for (int n = 0; n < 4; n++) {
                int gcol = j0 + wc * 64 + n * 16 + (lane & 15);
                float vdot = acc[m][n][j];
                unsigned long long p = (grow == gcol)
                    ? 0ull
                    : ((unsigned long long)f2mono(vdot) << 32) | (unsigned int)(~(unsigned int)gcol);
                best = p > best ? p : best;
            }
            #pragma unroll
            for (int s = 1; s < 16; s <<= 1) {
                unsigned long long o = shfl_xor_u64(best, s);
                best = o > best ? o : best;
            }
            if ((lane & 15) == 0)
                atomicMax(&rowmax[(size_t)v * B_N + grow], best);
        }
    }

    // ---- Epilogue B: transposed side (rows j0.., cols i0..), off-diag only ----
    if (!diag) {
        #pragma unroll
        for (int n = 0; n < 4; n++) {
            int growT = j0 + wc * 64 + n * 16 + (lane & 15);   // C column = transposed row
            unsigned long long best = 0ull;
            #pragma unroll
            for (int m = 0; m < 4; m++) {
                int ibase = i0 + wr * 64 + m * 16 + (lane >> 4) * 4;
                #pragma unroll
                for (int j = 0; j < 4; j++) {
                    int gi = ibase + j;                        // C row = transposed col
                    float vdot = acc[m][n][j];
                    unsigned long long p =
                        ((unsigned long long)f2mono(vdot) << 32) | (unsigned int)(~(unsigned int)gi);
                    best = p > best ? p : best;
                }
            }
            #pragma unroll
            for (int s = 16; s < 64; s <<= 1) {
                unsigned long long o = shfl_xor_u64(best, s);
                best = o > best ? o : best;
            }
            if (lane < 16)
                atomicMax(&rowmax[(size_t)v * B_N + growT], best);
        }
    }
}

// --- Kernel 3: decode loss directly from packed keys, reduce to scalar -----
// Key = (f2mono(dot) << 32) | ~col ; rows are unit-norm (bf16), so
// dist = sqrt(2 - 2*dot) with error ~2e-4 << 1.1e-2 threshold.
// Single block, fixed reduction tree -> deterministic.
__global__ __launch_bounds__(256) void kloss(const unsigned long long* __restrict__ rowmax,
                                             float* __restrict__ out) {
    int t = threadIdx.x;
    float acc = 0.f;
    for (int i = t; i < V_N * B_N; i += 256) {
        unsigned long long k = rowmax[i];
        float dot = mono2f((unsigned int)(k >> 32));
        float d2 = fmaxf(2.0f - 2.0f * dot, 0.0f);
        acc += -logf(sqrtf(d2) + EPS);
    }
    __shared__ float s[256];
    s[t] = acc;
    __syncthreads();
    #pragma unroll
    for (int step = 128; step > 0; step >>= 1) {
        if (t < step) s[t] += s[t + step];
        __syncthreads();
    }
    if (t == 0) out[0] = s[0] * (1.0f / (float)B_N);
}

extern "C" void kernel_launch(void* const* d_in, const int* in_sizes, int n_in,
                              void* d_out, int out_size, void* d_ws, size_t ws_size,
                              hipStream_t stream) {
    const float* x = (const float*)d_in[0];
    float* out = (float*)d_out;
    char* ws = (char*)d_ws;

    unsigned short* xbf = (unsigned short*)ws;                          // 16 MB
    unsigned long long* rowmax = (unsigned long long*)(ws + 16777216);  // 64 KB

    hipMemsetAsync(rowmax, 0, (size_t)V_N * B_N * sizeof(unsigned long long), stream);
    knorm<<<B_N * V_N, 256, 0, stream>>>(x, xbf);
    kargmax<<<dim3(NTRI, V_N), 256, 0, stream>>>(xbf, rowmax);
    kloss<<<1, 256, 0, stream>>>(rowmax, out);
}

// Round 9
// 93.045 us; speedup vs baseline: 1.3948x; 1.0297x over previous
//
#include <hip/hip_runtime.h>
#include <hip/hip_bf16.h>
#include <stdint.h>

#define B_N 4096
#define V_N 2
#define D_N 1024
#define EPS 1e-8f
#define NT 32                // 4096/128 tiles per dim
#define NTRI (NT*(NT+1)/2)   // 528 = 8*66 -> clean XCD chunking
#define NSTEP 32             // K-steps of BK=32

typedef __attribute__((ext_vector_type(8))) short short8;
typedef __attribute__((ext_vector_type(4))) float f32x4;

__device__ __forceinline__ unsigned int f2mono(float f) {
    unsigned int u = __float_as_uint(f);
    return (u & 0x80000000u) ? ~u : (u | 0x80000000u);
}

__device__ __forceinline__ float mono2f(unsigned int m) {
    unsigned int u = (m & 0x80000000u) ? (m ^ 0x80000000u) : ~m;
    return __uint_as_float(u);
}

__device__ __forceinline__ unsigned short f2bf(float f) {
    __hip_bfloat16 h = __float2bfloat16(f);
    return __builtin_bit_cast(unsigned short, h);
}

__device__ __forceinline__ unsigned long long shfl_xor_u64(unsigned long long v, int m) {
    unsigned int lo = (unsigned int)v, hi = (unsigned int)(v >> 32);
    lo = __shfl_xor(lo, m, 64);
    hi = __shfl_xor(hi, m, 64);
    return ((unsigned long long)hi << 32) | lo;
}

#define GLD16(src, dst) __builtin_amdgcn_global_load_lds(                      \
    (const __attribute__((address_space(1))) unsigned int*)(src),             \
    (__attribute__((address_space(3))) unsigned int*)(dst), 16, 0, 0)

// ---------------- Kernel 1: L2-normalize, emit bf16 (V,B,D) ----------------
__global__ __launch_bounds__(256) void knorm(const float* __restrict__ x,
                                             unsigned short* __restrict__ xbf) {
    int r = blockIdx.x;            // r = b*V + v  (input rows are contiguous)
    int b = r >> 1, v = r & 1;
    const float* row = x + (size_t)r * D_N;
    int t = threadIdx.x;
    float4 val = reinterpret_cast<const float4*>(row)[t];
    float ss = val.x * val.x + val.y * val.y + val.z * val.z + val.w * val.w;
    #pragma unroll
    for (int s = 32; s > 0; s >>= 1) ss += __shfl_xor(ss, s, 64);
    __shared__ float wsum[4];
    if ((t & 63) == 0) wsum[t >> 6] = ss;
    __syncthreads();
    float tot = wsum[0] + wsum[1] + wsum[2] + wsum[3];
    float rn = 1.0f / sqrtf(tot + EPS);
    ushort4 o;
    o.x = f2bf(val.x * rn);
    o.y = f2bf(val.y * rn);
    o.z = f2bf(val.z * rn);
    o.w = f2bf(val.w * rn);
    unsigned short* orow = xbf + ((size_t)v * B_N + b) * D_N;
    reinterpret_cast<ushort4*>(orow)[t] = o;
}

// ------- Kernel 2: per-view X·X^T, row-wise argmax, symmetric tiles --------
// 128x128 tile, 4 waves (2x2), 16x16x32 MFMA, BK=32 DOUBLE-buffered (32 KB),
// stage(t+1) -> s_waitcnt vmcnt(4) (counted, covers tile t; prefetch stays in
// flight) -> raw s_barrier -> ds_read+MFMA.  One barrier per step; NO
// __syncthreads in the loop (its vmcnt(0) drain was r8's latency exposure).
// Race-free: writes to buf^1 (window t) vs reads of buf^1 (windows t-1/t+1)
// are separated by barrier+vmcnt.  Swizzle f(row)=(row>>1)&3 (r5: 0 conflicts).
// 4 blocks/CU co-resident; T1 XCD chunking.
__global__ __launch_bounds__(256, 4) void kargmax(const unsigned short* __restrict__ xbf,
                                                  unsigned long long* __restrict__ rowmax) {
    __shared__ unsigned short lA[2 * 4096];   // 2 bufs x 128x32 bf16 = 16 KB
    __shared__ unsigned short lB[2 * 4096];   // 16 KB
    const int v = blockIdx.y;
    // T1: chunked XCD swizzle (bijective: 528 = 8*66)
    const int bx = (blockIdx.x & 7) * (NTRI / 8) + (blockIdx.x >> 3);
    int ti = (int)((sqrtf(8.f * (float)bx + 1.f) - 1.f) * 0.5f);
    while ((ti + 1) * (ti + 2) / 2 <= bx) ti++;
    while (ti * (ti + 1) / 2 > bx) ti--;
    const int tj = bx - ti * (ti + 1) / 2;
    const int i0 = ti * 128;
    const int j0 = tj * 128;
    const bool diag = (ti == tj);
    const unsigned short* Xv = xbf + (size_t)v * B_N * D_N;

    const int tid = threadIdx.x;
    const int wid = tid >> 6, lane = tid & 63;
    const int wr = wid >> 1, wc = wid & 1;

    f32x4 acc[4][4];
    #pragma unroll
    for (int m = 0; m < 4; m++)
        #pragma unroll
        for (int n = 0; n < 4; n++) acc[m][n] = (f32x4){0.f, 0.f, 0.f, 0.f};

    // Write side: lane l -> row l>>2 of a 16-row chunk, physical slot l&3;
    // source K-chunk = (l&3) ^ f(row), f(row) = (row>>1)&3 = (l>>3)&3.
    const int csw = ((lane & 3) ^ ((lane >> 3) & 3)) * 8;
    const unsigned short* pA = Xv + (size_t)(i0 + wid * 32 + (lane >> 2)) * D_N + csw;
    const unsigned short* pB = Xv + (size_t)(j0 + wid * 32 + (lane >> 2)) * D_N + csw;

    // Read side: K-chunk lane>>4 at row with row%16 = lane&15:
    // physical slot = (lane>>4) ^ ((row>>1)&3)   [r5-verified: 0 conflicts]
    const int rslot = (((lane >> 4) ^ ((lane & 15) >> 1)) & 3) * 8;

    // stage tile t into buf: 4 gload_lds per wave (2 A + 2 B)
#define STAGE(buf, t) do {                                                     \
    const unsigned short* _a = pA + (t) * 32;                                  \
    const unsigned short* _b = pB + (t) * 32;                                  \
    unsigned short* _dA = lA + (buf) * 4096 + wid * 1024;                      \
    unsigned short* _dB = lB + (buf) * 4096 + wid * 1024;                      \
    GLD16(_a,            _dA);                                                 \
    GLD16(_a + 16 * D_N, _dA + 512);                                           \
    GLD16(_b,            _dB);                                                 \
    GLD16(_b + 16 * D_N, _dB + 512);                                           \
} while (0)

#define COMPUTE(buf) do {                                                      \
    const unsigned short* _la = lA + (buf) * 4096;                             \
    const unsigned short* _lb = lB + (buf) * 4096;                             \
    short8 af[4], bfr[4];                                                      \
    _Pragma("unroll")                                                          \
    for (int m = 0; m < 4; m++)                                                \
        af[m] = *reinterpret_cast<const short8*>(                              \
            &_la[(wr * 64 + m * 16 + (lane & 15)) * 32 + rslot]);              \
    _Pragma("unroll")                                                          \
    for (int n = 0; n < 4; n++)                                                \
        bfr[n] = *reinterpret_cast<const short8*>(                             \
            &_lb[(wc * 64 + n * 16 + (lane & 15)) * 32 + rslot]);              \
    __builtin_amdgcn_s_setprio(1);                                             \
    _Pragma("unroll")                                                          \
    for (int m = 0; m < 4; m++)                                                \
        _Pragma("unroll")                                                      \
        for (int n = 0; n < 4; n++)                                            \
            acc[m][n] = __builtin_amdgcn_mfma_f32_16x16x32_bf16(               \
                af[m], bfr[n], acc[m][n], 0, 0, 0);                            \
    __builtin_amdgcn_s_setprio(0);                                             \
} while (0)

    // ---- Prologue: tile 0 in flight ----
    STAGE(0, 0);
    // ---- Main loop: 2x unrolled for static buf indices ----
    #pragma unroll 1
    for (int t = 0; t < NSTEP - 2; t += 2) {
        STAGE(1, t + 1);
        asm volatile("s_waitcnt vmcnt(4)" ::: "memory");   // tile t landed
        __builtin_amdgcn_s_barrier();
        COMPUTE(0);
        STAGE(0, t + 2);
        asm volatile("s_waitcnt vmcnt(4)" ::: "memory");   // tile t+1 landed
        __builtin_amdgcn_s_barrier();
        COMPUTE(1);
    }
    // ---- Tail: t = 30, 31 ----
    STAGE(1, NSTEP - 1);
    asm volatile("s_waitcnt vmcnt(4)" ::: "memory");
    __builtin_amdgcn_s_barrier();
    COMPUTE(0);
    asm volatile("s_waitcnt vmcnt(0)" ::: "memory");
    __builtin_amdgcn_s_barrier();
    COMPUTE(1);

    // ---- Epilogue A: row side (rows i0.., cols j0..) ----
    // C/D layout: col = lane&15, row = (lane>>4)*4 + reg  [m89/m91-verified]
    #pragma unroll
    for (int m = 0; m < 4; m++) {
        int rbase = i0 + wr * 64 + m * 16;
        #pragma unroll
        for (int j = 0; j < 4; j++) {
            int grow = rbase + (lane >> 4) * 4 + j;
            unsigned long long best = 0ull;
            #pragma unroll
            for (int n = 0; n < 4; n++) {
                int gcol = j0 + wc * 64 + n * 16 + (lane & 15);
                float vdot = acc[m][n][j];
                unsigned long long p = (grow == gcol)
                    ? 0ull
                    : ((unsigned long long)f2mono(vdot) << 32) | (unsigned int)(~(unsigned int)gcol);
                best = p > best ? p : best;
            }
            #pragma unroll
            for (int s = 1; s < 16; s <<= 1) {
                unsigned long long o = shfl_xor_u64(best, s);
                best = o > best ? o : best;
            }
            if ((lane & 15) == 0)
                atomicMax(&rowmax[(size_t)v * B_N + grow], best);
        }
    }

    // ---- Epilogue B: transposed side (rows j0.., cols i0..), off-diag only ----
    if (!diag) {
        #pragma unroll
        for (int n = 0; n < 4; n++) {
            int growT = j0 + wc * 64 + n * 16 + (lane & 15);   // C column = transposed row
            unsigned long long best = 0ull;
            #pragma unroll
            for (int m = 0; m < 4; m++) {
                int ibase = i0 + wr * 64 + m * 16 + (lane >> 4) * 4;
                #pragma unroll
                for (int j = 0; j < 4; j++) {
                    int gi = ibase + j;                        // C row = transposed col
                    float vdot = acc[m][n][j];
                    unsigned long long p =
                        ((unsigned long long)f2mono(vdot) << 32) | (unsigned int)(~(unsigned int)gi);
                    best = p > best ? p : best;
                }
            }
            #pragma unroll
            for (int s = 16; s < 64; s <<= 1) {
                unsigned long long o = shfl_xor_u64(best, s);
                best = o > best ? o : best;
            }
            if (lane < 16)
                atomicMax(&rowmax[(size_t)v * B_N + growT], best);
        }
    }
#undef STAGE
#undef COMPUTE
}

// --- Kernel 3: decode loss directly from packed keys, reduce to scalar -----
// Key = (f2mono(dot) << 32) | ~col ; rows are unit-norm (bf16), so
// dist = sqrt(2 - 2*dot) with error ~2e-4 << 1.1e-2 threshold.
// Single block, fixed reduction tree -> deterministic.
__global__ __launch_bounds__(256) void kloss(const unsigned long long* __restrict__ rowmax,
                                             float* __restrict__ out) {
    int t = threadIdx.x;
    float acc = 0.f;
    for (int i = t; i < V_N * B_N; i += 256) {
        unsigned long long k = rowmax[i];
        float dot = mono2f((unsigned int)(k >> 32));
        float d2 = fmaxf(2.0f - 2.0f * dot, 0.0f);
        acc += -logf(sqrtf(d2) + EPS);
    }
    __shared__ float s[256];
    s[t] = acc;
    __syncthreads();
    #pragma unroll
    for (int step = 128; step > 0; step >>= 1) {
        if (t < step) s[t] += s[t + step];
        __syncthreads();
    }
    if (t == 0) out[0] = s[0] * (1.0f / (float)B_N);
}

extern "C" void kernel_launch(void* const* d_in, const int* in_sizes, int n_in,
                              void* d_out, int out_size, void* d_ws, size_t ws_size,
                              hipStream_t stream) {
    const float* x = (const float*)d_in[0];
    float* out = (float*)d_out;
    char* ws = (char*)d_ws;

    unsigned short* xbf = (unsigned short*)ws;                          // 16 MB
    unsigned long long* rowmax = (unsigned long long*)(ws + 16777216);  // 64 KB

    hipMemsetAsync(rowmax, 0, (size_t)V_N * B_N * sizeof(unsigned long long), stream);
    knorm<<<B_N * V_N, 256, 0, stream>>>(x, xbf);
    kargmax<<<dim3(NTRI, V_N), 256, 0, stream>>>(xbf, rowmax);
    kloss<<<1, 256, 0, stream>>>(rowmax, out);
}